// Round 8
// baseline (202.893 us; speedup 1.0000x reference)
//
#include <hip/hip_runtime.h>
#include <stdint.h>

#define DI __device__ __forceinline__

typedef __attribute__((ext_vector_type(8))) short short8;
typedef __attribute__((ext_vector_type(4))) float f32x4;

DI float bf2f(unsigned short u){ union{unsigned int i; float f;} v; v.i = ((unsigned int)u)<<16; return v.f; }
DI unsigned short f2bf(float f){ union{float f; unsigned int i;} v; v.f=f; return (unsigned short)((v.i + 0x7fffu + ((v.i>>16)&1u))>>16); }
DI float siluf(float x){ return x/(1.f + __expf(-x)); }
DI f32x4 vzero(){ f32x4 z; z[0]=0.f;z[1]=0.f;z[2]=0.f;z[3]=0.f; return z; }
DI f32x4 vsplat(float x){ f32x4 z; z[0]=x;z[1]=x;z[2]=x;z[3]=x; return z; }

// ---------------- weight prep ----------------
struct PrepArgs {
  const float* W[6];
  const float* g[6];
  unsigned short* Wt[6];
  int C[6];
};

__global__ __launch_bounds__(256) void prep_transpose(PrepArgs a){
  int m = blockIdx.z;
  int C = a.C[m];
  int nt = C >> 5;
  if ((int)blockIdx.x >= nt || (int)blockIdx.y >= nt) return;
  __shared__ float tile[32][33];
  int col = threadIdx.x & 31;
  int rr  = threadIdx.x >> 5;
  const float* W = a.W[m];
  const float* g = a.g[m];
  #pragma unroll
  for (int p=0;p<4;++p){
    int r = rr + p*8;
    int cK = blockIdx.x*32 + r;
    int dN = blockIdx.y*32 + col;
    float v = W[(size_t)cK*C + dN];
    if (g) v *= g[cK];
    tile[r][col] = v;
  }
  __syncthreads();
  unsigned short* Wt = a.Wt[m];
  #pragma unroll
  for (int p=0;p<4;++p){
    int r = rr + p*8;
    int dN = blockIdx.y*32 + r;
    int cK = blockIdx.x*32 + col;
    Wt[(size_t)dN*C + cK] = f2bf(tile[col][r]);  // Wt[d][c] = g[c]*W[c][d]
  }
}

struct ColArgs {
  const float* W[4]; const float* g[4]; const float* b[4]; const float* extra[4];
  float* ocs[4]; float* obs[4]; int C[4];
};

__global__ __launch_bounds__(256) void prep_colsum(ColArgs a){
  int j = blockIdx.y;
  int C = a.C[j];
  int d0 = blockIdx.x * 64;
  if (d0 >= C) return;
  int dl = threadIdx.x & 63;
  int g  = threadIdx.x >> 6;
  int d  = d0 + dl;
  const float* W = a.W[j]; const float* gv = a.g[j]; const float* bv = a.b[j];
  float cs = 0.f, bs = 0.f;
  for (int c = g; c < C; c += 4){
    float gc = gv[c], bc = bv[c];
    float w = W[(size_t)c*C + d];
    cs += gc*w;
    bs += bc*w;
  }
  __shared__ float rcs[4][64], rbs[4][64];
  rcs[g][dl] = cs; rbs[g][dl] = bs;
  __syncthreads();
  if (threadIdx.x < 64){
    float c0 = rcs[0][dl]+rcs[1][dl]+rcs[2][dl]+rcs[3][dl];
    float b0 = rbs[0][dl]+rbs[1][dl]+rbs[2][dl]+rbs[3][dl];
    if (a.extra[j]) b0 += a.extra[j][d];
    a.ocs[j][d] = c0;
    a.obs[j][d] = b0;
  }
}

// ---------------- fused branch kernel v4 ----------------
// Full-weight staging: ONE barrier pair per GEMM pass (v3 had one per 64-wide K chunk).
// x-slice prefetched into registers during the previous GEMM (T14 split).
// Wave grid 2(px) x 4(d) for both branches.
// C=128: PX=64, Ws=32KB slot restaged per pass, LDS ~52.5KB -> 2 blocks/CU.
// C=256: PX=32, Ws=128KB (full W resident per pass), LDS ~148.5KB -> 1 block/CU.
template<int C, int PX>
__global__ __launch_bounds__(512) void fusedv4(
    const float* __restrict__ x,
    const unsigned short* __restrict__ WtCur,
    const unsigned short* __restrict__ WtRef,
    const unsigned short* __restrict__ WtConv,
    const float* __restrict__ colC, const float* __restrict__ biasC,
    const float* __restrict__ colR, const float* __restrict__ biasR,
    const float* __restrict__ bns, const float* __restrict__ bnb,
    float* __restrict__ out, int HW){
  constexpr int T = 5;
  constexpr int DSPAN = C/4;           // d-cols per wave (32 or 64)
  constexpr int NF = DSPAN/16;         // 2 or 4
  constexpr int MROWS = PX/2;          // px rows per wave (32 or 16)
  constexpr int MF = MROWS/16;         // 2 or 1
  constexpr int KS = C/32;             // 4 or 8
  constexpr int G = 512/PX;            // LN stat groups (8 or 16)
  constexpr int PER = (C/8)/G;         // = 2 both
  constexpr int ABYTES = PX*2*C;       // 16KB both
  constexpr int WBYTES = 2*C*C;        // 32KB / 128KB
  constexpr int LDS_TOT = ABYTES + WBYTES + 4096 + PX*8;
  static_assert((size_t)PX*(C+1)*4 <= (size_t)ABYTES + WBYTES, "pool fits");

  __shared__ __align__(16) char L[LDS_TOT];
  char* Ws = L + ABYTES;
  float* red = (float*)(L + ABYTES + WBYTES);
  float* smean = (float*)(L + ABYTES + WBYTES + 4096);
  float* srstd = smean + PX;

  int px0 = blockIdx.x*PX;
  int b = px0 / HW, hw0 = px0 % HW;
  int tid = threadIdx.x, lane = tid&63, wid = tid>>6;
  int wr = wid>>2, wc = wid&3;
  int cl = lane&15, hi = lane>>4;
  const float* xbase = x + (size_t)b*C*T*HW + hw0;

  // ---- issue next x-slice loads into regs (prefetch half) ----
  auto loadX = [&](const float* xb, f32x4 (&p)[4]){
    #pragma unroll
    for (int i=0;i<4;++i){
      int c, pq;
      if constexpr (C==128){ c = wid*16 + cl; pq = i*4 + hi; }
      else                 { c = wid*32 + (i&1)*16 + cl; pq = (i>>1)*4 + hi; }
      p[i] = *(const f32x4*)(xb + (size_t)c*(T*HW) + pq*4);
    }
  };
  // ---- write prefetched regs into swizzled LDS As (commit half) ----
  auto commitX = [&](const f32x4 (&p)[4]){
    #pragma unroll
    for (int i=0;i<4;++i){
      int c, pq;
      if constexpr (C==128){ c = wid*16 + cl; pq = i*4 + hi; }
      else                 { c = wid*32 + (i&1)*16 + cl; pq = (i>>1)*4 + hi; }
      #pragma unroll
      for (int j=0;j<4;++j){
        int px = pq*4 + j;
        *(unsigned short*)(L + px*(2*C) + (((c>>3) ^ (px&7))*16) + (c&7)*2) = f2bf(p[i][j]);
      }
    }
  };

  auto statsX = [&](){
    int px = tid & (PX-1), g = tid / PX;
    float s=0.f, q=0.f;
    #pragma unroll
    for (int k2=0;k2<PER;++k2){
      int ch = g*PER + k2;
      short8 v = *(const short8*)(L + px*(2*C) + ((ch ^ (px&7))*16));
      #pragma unroll
      for (int e=0;e<8;++e){ float f = bf2f((unsigned short)v[e]); s += f; q += f*f; }
    }
    red[g*PX+px] = s; red[512 + g*PX+px] = q;
    __syncthreads();
    if (tid < PX){
      float ss=0.f, qq=0.f;
      #pragma unroll
      for (int gg=0; gg<G; ++gg){ ss += red[gg*PX+tid]; qq += red[512+gg*PX+tid]; }
      float m = ss*(1.f/C);
      float var = fmaxf(qq*(1.f/C) - m*m, 0.f);
      smean[tid] = m;
      srstd[tid] = rsqrtf(var + 1e-5f);
    }
    __syncthreads();
  };

  // ---- full-weight stage: [C rows(d)][C cols(c)] swizzled, one shot ----
  auto stageW = [&](const unsigned short* Wt){
    constexpr int CH = C/8;
    #pragma unroll
    for (int it=0; it<(C*CH)/512; ++it){
      int i = tid + it*512, row = i/CH, ch = i%CH;
      short8 v = *(const short8*)(Wt + (size_t)row*C + ch*8);
      *(short8*)(Ws + row*(2*C) + ((ch ^ (row&7))*16)) = v;
    }
  };

  // ---- one full-K GEMM pass: no internal barriers ----
  auto gemm = [&](f32x4 (&acc)[MF][NF]){
    #pragma unroll
    for (int ks=0;ks<KS;++ks){
      short8 af[MF], bf8[NF];
      #pragma unroll
      for (int mf=0;mf<MF;++mf){
        int row = wr*MROWS + mf*16 + cl;
        int chs = (ks*4 + hi) ^ (row&7);
        af[mf] = *(const short8*)(L + row*(2*C) + chs*16);
      }
      #pragma unroll
      for (int nf=0;nf<NF;++nf){
        int row = wc*DSPAN + nf*16 + cl;
        int chs = (ks*4 + hi) ^ (row&7);
        bf8[nf] = *(const short8*)(Ws + row*(2*C) + chs*16);
      }
      #pragma unroll
      for (int mf=0;mf<MF;++mf)
        #pragma unroll
        for (int nf=0;nf<NF;++nf)
          acc[mf][nf] = __builtin_amdgcn_mfma_f32_16x16x32_bf16(af[mf], bf8[nf], acc[mf][nf], 0,0,0);
    }
  };

  // ---- per-thread persistent state (~48 regs) ----
  float csR[NF], biR[NF], scn[NF], sbn[NF];
  #pragma unroll
  for (int nf=0;nf<NF;++nf){
    int d = wc*DSPAN + nf*16 + cl;
    csR[nf] = colR[d]; biR[nf] = biasR[d];
    scn[nf] = bns[d];  sbn[nf] = bnb[d];
  }
  unsigned short pv[NF][MF*4], cvr[NF][MF*4];
  f32x4 mx[NF][MF], sm[NF][MF];
  #pragma unroll
  for (int nf=0;nf<NF;++nf)
    #pragma unroll
    for (int mf=0;mf<MF;++mf){ mx[nf][mf] = vsplat(-3.0e38f); sm[nf][mf] = vzero(); }

  f32x4 p[4];

  // ---- phase 0: cur projection -> pv (P) and cvr (raw cur) in registers ----
  loadX(xbase + (size_t)(T-1)*HW, p);
  stageW(WtCur);
  commitX(p);
  __syncthreads();
  statsX();
  loadX(xbase, p);                    // prefetch t=0 under cur GEMM
  {
    f32x4 acc[MF][NF];
    #pragma unroll
    for (int mf=0;mf<MF;++mf)
      #pragma unroll
      for (int nf=0;nf<NF;++nf) acc[mf][nf]=vzero();
    gemm(acc);
    #pragma unroll
    for (int nf=0;nf<NF;++nf){
      int dg = wc*DSPAN + nf*16 + cl;
      float cs = colC[dg], bi = biasC[dg];
      #pragma unroll
      for (int mf=0;mf<MF;++mf)
        #pragma unroll
        for (int r=0;r<4;++r){
          int pl = wr*MROWS + mf*16 + hi*4 + r;
          float P = srstd[pl]*(acc[mf][nf][r] - smean[pl]*cs) + bi;
          pv[nf][mf*4+r] = f2bf(P);
          cvr[nf][mf*4+r] = *(const unsigned short*)(L + pl*(2*C) + (((dg>>3)^(pl&7))*16) + (dg&7)*2);
        }
    }
  }

  // ---- t loop ----
  for (int t=0;t<4;++t){
    __syncthreads();                  // As/Ws reads done (cur GEMM+cv epi, or prev conv)
    stageW(WtRef);
    commitX(p);
    __syncthreads();
    statsX();
    if (t < 3) loadX(xbase + (size_t)(t+1)*HW, p);   // prefetch under ref+conv GEMMs

    f32x4 acc[MF][NF];
    #pragma unroll
    for (int mf=0;mf<MF;++mf)
      #pragma unroll
      for (int nf=0;nf<NF;++nf) acc[mf][nf]=vzero();
    gemm(acc);                        // ref GEMM (reads As=x_t, Ws=Wref)

    __syncthreads();                  // ref GEMM reads complete; As/Ws reusable
    // h epilogue -> overwrite As; stage Wconv -> Ws (disjoint regions)
    #pragma unroll
    for (int nf=0;nf<NF;++nf){
      int dg = wc*DSPAN + nf*16 + cl;
      #pragma unroll
      for (int mf=0;mf<MF;++mf)
        #pragma unroll
        for (int r=0;r<4;++r){
          int pl = wr*MROWS + mf*16 + hi*4 + r;
          float pre = srstd[pl]*(acc[mf][nf][r] - smean[pl]*csR[nf]) + biR[nf] + bf2f(pv[nf][mf*4+r]);
          float hv = bf2f(cvr[nf][mf*4+r]) + siluf(pre);
          *(unsigned short*)(L + pl*(2*C) + (((dg>>3)^(pl&7))*16) + (dg&7)*2) = f2bf(hv);
        }
    }
    stageW(WtConv);
    __syncthreads();

    f32x4 acc2[MF][NF];
    #pragma unroll
    for (int mf=0;mf<MF;++mf)
      #pragma unroll
      for (int nf=0;nf<NF;++nf) acc2[mf][nf]=vzero();
    gemm(acc2);                       // conv GEMM (reads As=h, Ws=Wconv)
    #pragma unroll
    for (int nf=0;nf<NF;++nf)
      #pragma unroll
      for (int mf=0;mf<MF;++mf)
        #pragma unroll
        for (int r=0;r<4;++r){
          float y = siluf(acc2[mf][nf][r]*scn[nf] + sbn[nf]);
          mx[nf][mf][r] = fmaxf(mx[nf][mf][r], y);
          sm[nf][mf][r] += y;
        }
  }

  // ---- pool -> LDS (stride C+1 over As+Ws region) -> coalesced transposed store ----
  __syncthreads();
  float* pool = (float*)L;
  #pragma unroll
  for (int nf=0;nf<NF;++nf){
    int dl = wc*DSPAN + nf*16 + cl;
    #pragma unroll
    for (int mf=0;mf<MF;++mf)
      #pragma unroll
      for (int r=0;r<4;++r){
        int pl = wr*MROWS + mf*16 + hi*4 + r;
        pool[pl*(C+1) + dl] = mx[nf][mf][r] + 0.25f*sm[nf][mf][r];
      }
  }
  __syncthreads();
  constexpr int PQn = PX/4;
  #pragma unroll
  for (int it=0; it<(C*PQn)/512; ++it){
    int i = tid + it*512;
    int dl = i / PQn, pq = i % PQn;
    f32x4 vv;
    #pragma unroll
    for (int k=0;k<4;++k) vv[k] = pool[(pq*4+k)*(C+1) + dl];
    *(f32x4*)(out + (size_t)(b*C + dl)*HW + hw0 + pq*4) = vv;
  }
}

// ---------------- host ----------------
extern "C" void kernel_launch(void* const* d_in, const int* in_sizes, int n_in,
                              void* d_out, int out_size, void* d_ws, size_t ws_size,
                              hipStream_t stream) {
  (void)in_sizes; (void)n_in; (void)out_size; (void)ws_size;
  const float* x2    = (const float*)d_in[0];
  const float* x1    = (const float*)d_in[1];
  const float* g2c   = (const float*)d_in[3];
  const float* b2c   = (const float*)d_in[4];
  const float* g2r   = (const float*)d_in[5];
  const float* b2r   = (const float*)d_in[6];
  const float* W2cur = (const float*)d_in[7];
  const float* W2ref = (const float*)d_in[8];
  const float* bias2 = (const float*)d_in[9];
  const float* convw2= (const float*)d_in[10];
  const float* bns2  = (const float*)d_in[11];
  const float* bnb2  = (const float*)d_in[12];
  const float* g1c   = (const float*)d_in[13];
  const float* b1c   = (const float*)d_in[14];
  const float* g1r   = (const float*)d_in[15];
  const float* b1r   = (const float*)d_in[16];
  const float* W1cur = (const float*)d_in[17];
  const float* W1ref = (const float*)d_in[18];
  const float* bias1 = (const float*)d_in[19];
  const float* convw1= (const float*)d_in[20];
  const float* bns1  = (const float*)d_in[21];
  const float* bnb1  = (const float*)d_in[22];

  const int C2 = 128, C1 = 256;
  const int NP2 = 8*64*64, NP1 = 8*32*32;
  const int HW2 = 4096, HW1 = 1024;

  char* ws = (char*)d_ws;
  size_t off = 0;
  auto alloc = [&](size_t bytes){ size_t o = off; off = (off + bytes + 255) & ~(size_t)255; return o; };
  size_t oWtC2 = alloc((size_t)C2*C2*2), oWtR2 = alloc((size_t)C2*C2*2), oWtV2 = alloc((size_t)C2*C2*2);
  size_t oWtC1 = alloc((size_t)C1*C1*2), oWtR1 = alloc((size_t)C1*C1*2), oWtV1 = alloc((size_t)C1*C1*2);
  size_t oColC2 = alloc(C2*4), oBiasC2 = alloc(C2*4), oColR2 = alloc(C2*4), oBiasR2 = alloc(C2*4);
  size_t oColC1 = alloc(C1*4), oBiasC1 = alloc(C1*4), oColR1 = alloc(C1*4), oBiasR1 = alloc(C1*4);

  unsigned short* WtC2 = (unsigned short*)(ws + oWtC2);
  unsigned short* WtR2 = (unsigned short*)(ws + oWtR2);
  unsigned short* WtV2 = (unsigned short*)(ws + oWtV2);
  unsigned short* WtC1 = (unsigned short*)(ws + oWtC1);
  unsigned short* WtR1 = (unsigned short*)(ws + oWtR1);
  unsigned short* WtV1 = (unsigned short*)(ws + oWtV1);
  float* ColC2 = (float*)(ws + oColC2); float* BiasC2 = (float*)(ws + oBiasC2);
  float* ColR2 = (float*)(ws + oColR2); float* BiasR2 = (float*)(ws + oBiasR2);
  float* ColC1 = (float*)(ws + oColC1); float* BiasC1 = (float*)(ws + oBiasC1);
  float* ColR1 = (float*)(ws + oColR1); float* BiasR1 = (float*)(ws + oBiasR1);

  PrepArgs pa;
  pa.W[0]=W2cur;  pa.g[0]=g2c;     pa.Wt[0]=WtC2; pa.C[0]=C2;
  pa.W[1]=W2ref;  pa.g[1]=g2r;     pa.Wt[1]=WtR2; pa.C[1]=C2;
  pa.W[2]=convw2; pa.g[2]=nullptr; pa.Wt[2]=WtV2; pa.C[2]=C2;
  pa.W[3]=W1cur;  pa.g[3]=g1c;     pa.Wt[3]=WtC1; pa.C[3]=C1;
  pa.W[4]=W1ref;  pa.g[4]=g1r;     pa.Wt[4]=WtR1; pa.C[4]=C1;
  pa.W[5]=convw1; pa.g[5]=nullptr; pa.Wt[5]=WtV1; pa.C[5]=C1;
  prep_transpose<<<dim3(8,8,6), 256, 0, stream>>>(pa);

  ColArgs ca;
  ca.W[0]=W2cur; ca.g[0]=g2c; ca.b[0]=b2c; ca.extra[0]=nullptr; ca.ocs[0]=ColC2; ca.obs[0]=BiasC2; ca.C[0]=C2;
  ca.W[1]=W2ref; ca.g[1]=g2r; ca.b[1]=b2r; ca.extra[1]=bias2;   ca.ocs[1]=ColR2; ca.obs[1]=BiasR2; ca.C[1]=C2;
  ca.W[2]=W1cur; ca.g[2]=g1c; ca.b[2]=b1c; ca.extra[2]=nullptr; ca.ocs[2]=ColC1; ca.obs[2]=BiasC1; ca.C[2]=C1;
  ca.W[3]=W1ref; ca.g[3]=g1r; ca.b[3]=b1r; ca.extra[3]=bias1;   ca.ocs[3]=ColR1; ca.obs[3]=BiasR1; ca.C[3]=C1;
  prep_colsum<<<dim3(4, 4), 256, 0, stream>>>(ca);

  float* out2 = (float*)d_out;
  float* out1 = out2 + (size_t)8*C2*HW2;

  fusedv4<128,64><<<NP2/64, 512, 0, stream>>>(
      x2, WtC2, WtR2, WtV2, ColC2, BiasC2, ColR2, BiasR2, bns2, bnb2, out2, HW2);
  fusedv4<256,32><<<NP1/32, 512, 0, stream>>>(
      x1, WtC1, WtR1, WtV1, ColC1, BiasC1, ColR1, BiasR1, bns1, bnb1, out1, HW1);
}

// Round 9
// 146.882 us; speedup vs baseline: 1.3813x; 1.3813x over previous
//
#include <hip/hip_runtime.h>
#include <stdint.h>

#define DI __device__ __forceinline__

typedef __attribute__((ext_vector_type(8))) short short8;
typedef __attribute__((ext_vector_type(4))) float f32x4;

DI float bf2f(unsigned short u){ union{unsigned int i; float f;} v; v.i = ((unsigned int)u)<<16; return v.f; }
DI unsigned short f2bf(float f){ union{float f; unsigned int i;} v; v.f=f; return (unsigned short)((v.i + 0x7fffu + ((v.i>>16)&1u))>>16); }
DI float siluf(float x){ return x/(1.f + __expf(-x)); }
DI f32x4 vzero(){ f32x4 z; z[0]=0.f;z[1]=0.f;z[2]=0.f;z[3]=0.f; return z; }
DI f32x4 vsplat(float x){ f32x4 z; z[0]=x;z[1]=x;z[2]=x;z[3]=x; return z; }

// ---------------- weight prep ----------------
struct PrepArgs {
  const float* W[6];
  const float* g[6];
  unsigned short* Wt[6];
  int C[6];
};

__global__ __launch_bounds__(256) void prep_transpose(PrepArgs a){
  int m = blockIdx.z;
  int C = a.C[m];
  int nt = C >> 5;
  if ((int)blockIdx.x >= nt || (int)blockIdx.y >= nt) return;
  __shared__ float tile[32][33];
  int col = threadIdx.x & 31;
  int rr  = threadIdx.x >> 5;
  const float* W = a.W[m];
  const float* g = a.g[m];
  #pragma unroll
  for (int p=0;p<4;++p){
    int r = rr + p*8;
    int cK = blockIdx.x*32 + r;
    int dN = blockIdx.y*32 + col;
    float v = W[(size_t)cK*C + dN];
    if (g) v *= g[cK];
    tile[r][col] = v;
  }
  __syncthreads();
  unsigned short* Wt = a.Wt[m];
  #pragma unroll
  for (int p=0;p<4;++p){
    int r = rr + p*8;
    int dN = blockIdx.y*32 + r;
    int cK = blockIdx.x*32 + col;
    Wt[(size_t)dN*C + cK] = f2bf(tile[col][r]);  // Wt[d][c] = g[c]*W[c][d]
  }
}

struct ColArgs {
  const float* W[4]; const float* g[4]; const float* b[4]; const float* extra[4];
  float* ocs[4]; float* obs[4]; int C[4];
};

__global__ __launch_bounds__(256) void prep_colsum(ColArgs a){
  int j = blockIdx.y;
  int C = a.C[j];
  int d0 = blockIdx.x * 64;
  if (d0 >= C) return;
  int dl = threadIdx.x & 63;
  int g  = threadIdx.x >> 6;
  int d  = d0 + dl;
  const float* W = a.W[j]; const float* gv = a.g[j]; const float* bv = a.b[j];
  float cs = 0.f, bs = 0.f;
  for (int c = g; c < C; c += 4){
    float gc = gv[c], bc = bv[c];
    float w = W[(size_t)c*C + d];
    cs += gc*w;
    bs += bc*w;
  }
  __shared__ float rcs[4][64], rbs[4][64];
  rcs[g][dl] = cs; rbs[g][dl] = bs;
  __syncthreads();
  if (threadIdx.x < 64){
    float c0 = rcs[0][dl]+rcs[1][dl]+rcs[2][dl]+rcs[3][dl];
    float b0 = rbs[0][dl]+rbs[1][dl]+rbs[2][dl]+rbs[3][dl];
    if (a.extra[j]) b0 += a.extra[j][d];
    a.ocs[j][d] = c0;
    a.obs[j][d] = b0;
  }
}

// ---------------- fused branch kernel v5 ----------------
// No weight LDS: B-fragments read directly from global (L2-hot weights).
// 256 threads / 4 waves, wave grid 1(px) x 4(d). LDS = As(8KB)+stats only.
// C=128: PX=32, 1024 blocks.  C=256: PX=16, 512 blocks.  3-4 blocks/CU ->
// cross-block latency hiding; ~6 barriers/t but other blocks fill the stalls.
template<int C, int PX>
__global__ __launch_bounds__(256) void fusedv5(
    const float* __restrict__ x,
    const unsigned short* __restrict__ WtCur,
    const unsigned short* __restrict__ WtRef,
    const unsigned short* __restrict__ WtConv,
    const float* __restrict__ colC, const float* __restrict__ biasC,
    const float* __restrict__ colR, const float* __restrict__ biasR,
    const float* __restrict__ bns, const float* __restrict__ bnb,
    float* __restrict__ out, int HW){
  constexpr int T = 5;
  constexpr int DSPAN = C/4;           // d-cols per wave (32 or 64)
  constexpr int NF = DSPAN/16;         // 2 or 4
  constexpr int MF = PX/16;            // 2 or 1 (MROWS == PX, wr == 0)
  constexpr int KS = C/32;             // 4 or 8
  constexpr int G = 256/PX;            // LN stat groups (8 or 16)
  constexpr int PER = (C/8)/G;         // = 2 both
  constexpr int PQn = PX/4;            // px quads (8 or 4)
  constexpr int ABYTES = PX*2*C;       // 8KB both
  constexpr int POOLB = PX*(C+1)*4;    // ~16.5KB
  constexpr int LDS_TOT = (ABYTES + 2048 + PX*8 > POOLB) ? (ABYTES + 2048 + PX*8) : POOLB;

  __shared__ __align__(16) char L[LDS_TOT];
  float* red = (float*)(L + ABYTES);
  float* smean = (float*)(L + ABYTES + 2048);
  float* srstd = smean + PX;

  int px0 = blockIdx.x*PX;
  int b = px0 / HW, hw0 = px0 % HW;
  int tid = threadIdx.x, lane = tid&63, wc = tid>>6;
  int cl = lane&15, hi = lane>>4;
  const float* xbase = x + (size_t)b*C*T*HW + hw0;

  // ---- x-slice prefetch (regs) + commit (swizzled LDS) ----
  // mapping: contiguous lanes cover a full row: C=128: c=(tid>>3)+i*32, pq=tid&7
  //          C=256: c=(tid>>2)+i*64, pq=tid&3
  auto loadX = [&](const float* xb, f32x4 (&p)[4]){
    #pragma unroll
    for (int i=0;i<4;++i){
      int c, pq;
      if constexpr (C==128){ c = (tid>>3) + i*32; pq = tid&7; }
      else                 { c = (tid>>2) + i*64; pq = tid&3; }
      p[i] = *(const f32x4*)(xb + (size_t)c*(T*HW) + pq*4);
    }
  };
  auto commitX = [&](const f32x4 (&p)[4]){
    #pragma unroll
    for (int i=0;i<4;++i){
      int c, pq;
      if constexpr (C==128){ c = (tid>>3) + i*32; pq = tid&7; }
      else                 { c = (tid>>2) + i*64; pq = tid&3; }
      #pragma unroll
      for (int j=0;j<4;++j){
        int px = pq*4 + j;
        *(unsigned short*)(L + px*(2*C) + (((c>>3) ^ (px&7))*16) + (c&7)*2) = f2bf(p[i][j]);
      }
    }
  };

  auto statsX = [&](){
    int px = tid & (PX-1), g = tid / PX;
    float s=0.f, q=0.f;
    #pragma unroll
    for (int k2=0;k2<PER;++k2){
      int ch = g*PER + k2;
      short8 v = *(const short8*)(L + px*(2*C) + ((ch ^ (px&7))*16));
      #pragma unroll
      for (int e=0;e<8;++e){ float f = bf2f((unsigned short)v[e]); s += f; q += f*f; }
    }
    red[g*PX+px] = s; red[256 + g*PX+px] = q;
    __syncthreads();
    if (tid < PX){
      float ss=0.f, qq=0.f;
      #pragma unroll
      for (int gg=0; gg<G; ++gg){ ss += red[gg*PX+tid]; qq += red[256+gg*PX+tid]; }
      float m = ss*(1.f/C);
      float var = fmaxf(qq*(1.f/C) - m*m, 0.f);
      smean[tid] = m;
      srstd[tid] = rsqrtf(var + 1e-5f);
    }
    __syncthreads();
  };

  // ---- GEMM: A from LDS, B fragments DIRECT from global (L2-hot) ----
  auto gemm = [&](const unsigned short* __restrict__ Wt, f32x4 (&acc)[MF][NF]){
    #pragma unroll
    for (int ks=0;ks<KS;++ks){
      short8 bf8[NF];
      #pragma unroll
      for (int nf=0;nf<NF;++nf){
        int row = wc*DSPAN + nf*16 + cl;
        bf8[nf] = *(const short8*)(Wt + (size_t)row*C + ks*32 + hi*8);
      }
      short8 af[MF];
      #pragma unroll
      for (int mf=0;mf<MF;++mf){
        int row = mf*16 + cl;
        int chs = (ks*4 + hi) ^ (row&7);
        af[mf] = *(const short8*)(L + row*(2*C) + chs*16);
      }
      #pragma unroll
      for (int mf=0;mf<MF;++mf)
        #pragma unroll
        for (int nf=0;nf<NF;++nf)
          acc[mf][nf] = __builtin_amdgcn_mfma_f32_16x16x32_bf16(af[mf], bf8[nf], acc[mf][nf], 0,0,0);
    }
  };

  // ---- per-thread persistent state ----
  float csR[NF], biR[NF], scn[NF], sbn[NF];
  #pragma unroll
  for (int nf=0;nf<NF;++nf){
    int d = wc*DSPAN + nf*16 + cl;
    csR[nf] = colR[d]; biR[nf] = biasR[d];
    scn[nf] = bns[d];  sbn[nf] = bnb[d];
  }
  unsigned short pv[NF][MF*4], cvr[NF][MF*4];
  f32x4 mx[NF][MF], sm[NF][MF];
  #pragma unroll
  for (int nf=0;nf<NF;++nf)
    #pragma unroll
    for (int mf=0;mf<MF;++mf){ mx[nf][mf] = vsplat(-3.0e38f); sm[nf][mf] = vzero(); }

  f32x4 p[4];

  // ---- phase 0: cur projection -> pv (P) and cvr (raw cur) in registers ----
  loadX(xbase + (size_t)(T-1)*HW, p);
  commitX(p);
  __syncthreads();
  statsX();
  loadX(xbase, p);                     // prefetch t=0 under cur GEMM
  {
    f32x4 acc[MF][NF];
    #pragma unroll
    for (int mf=0;mf<MF;++mf)
      #pragma unroll
      for (int nf=0;nf<NF;++nf) acc[mf][nf]=vzero();
    gemm(WtCur, acc);
    #pragma unroll
    for (int nf=0;nf<NF;++nf){
      int dg = wc*DSPAN + nf*16 + cl;
      float cs = colC[dg], bi = biasC[dg];
      #pragma unroll
      for (int mf=0;mf<MF;++mf)
        #pragma unroll
        for (int r=0;r<4;++r){
          int pl = mf*16 + hi*4 + r;
          float P = srstd[pl]*(acc[mf][nf][r] - smean[pl]*cs) + bi;
          pv[nf][mf*4+r] = f2bf(P);
          cvr[nf][mf*4+r] = *(const unsigned short*)(L + pl*(2*C) + (((dg>>3)^(pl&7))*16) + (dg&7)*2);
        }
    }
  }

  // ---- t loop ----
  for (int t=0;t<4;++t){
    __syncthreads();                   // As reads done (cur epi or prev conv)
    commitX(p);
    __syncthreads();
    statsX();
    if (t < 3) loadX(xbase + (size_t)(t+1)*HW, p);  // prefetch under GEMMs

    f32x4 acc[MF][NF];
    #pragma unroll
    for (int mf=0;mf<MF;++mf)
      #pragma unroll
      for (int nf=0;nf<NF;++nf) acc[mf][nf]=vzero();
    gemm(WtRef, acc);                  // ref GEMM (reads As = x_t)

    __syncthreads();                   // all waves' x_t reads complete
    // h epilogue -> overwrite As with h
    #pragma unroll
    for (int nf=0;nf<NF;++nf){
      int dg = wc*DSPAN + nf*16 + cl;
      #pragma unroll
      for (int mf=0;mf<MF;++mf)
        #pragma unroll
        for (int r=0;r<4;++r){
          int pl = mf*16 + hi*4 + r;
          float pre = srstd[pl]*(acc[mf][nf][r] - smean[pl]*csR[nf]) + biR[nf] + bf2f(pv[nf][mf*4+r]);
          float hv = bf2f(cvr[nf][mf*4+r]) + siluf(pre);
          *(unsigned short*)(L + pl*(2*C) + (((dg>>3)^(pl&7))*16) + (dg&7)*2) = f2bf(hv);
        }
    }
    __syncthreads();                   // h visible to all waves

    f32x4 acc2[MF][NF];
    #pragma unroll
    for (int mf=0;mf<MF;++mf)
      #pragma unroll
      for (int nf=0;nf<NF;++nf) acc2[mf][nf]=vzero();
    gemm(WtConv, acc2);                // conv GEMM (reads As = h)
    #pragma unroll
    for (int nf=0;nf<NF;++nf)
      #pragma unroll
      for (int mf=0;mf<MF;++mf)
        #pragma unroll
        for (int r=0;r<4;++r){
          float y = siluf(acc2[mf][nf][r]*scn[nf] + sbn[nf]);
          mx[nf][mf][r] = fmaxf(mx[nf][mf][r], y);
          sm[nf][mf][r] += y;
        }
  }

  // ---- pool -> LDS (stride C+1) -> coalesced transposed store ----
  __syncthreads();
  float* pool = (float*)L;
  #pragma unroll
  for (int nf=0;nf<NF;++nf){
    int dl = wc*DSPAN + nf*16 + cl;
    #pragma unroll
    for (int mf=0;mf<MF;++mf)
      #pragma unroll
      for (int r=0;r<4;++r){
        int pl = mf*16 + hi*4 + r;
        pool[pl*(C+1) + dl] = mx[nf][mf][r] + 0.25f*sm[nf][mf][r];
      }
  }
  __syncthreads();
  #pragma unroll
  for (int it=0; it<(C*PQn)/256; ++it){
    int i = tid + it*256;
    int dl = i / PQn, pq = i % PQn;
    f32x4 vv;
    #pragma unroll
    for (int k=0;k<4;++k) vv[k] = pool[(pq*4+k)*(C+1) + dl];
    *(f32x4*)(out + (size_t)(b*C + dl)*HW + hw0 + pq*4) = vv;
  }
}

// ---------------- host ----------------
extern "C" void kernel_launch(void* const* d_in, const int* in_sizes, int n_in,
                              void* d_out, int out_size, void* d_ws, size_t ws_size,
                              hipStream_t stream) {
  (void)in_sizes; (void)n_in; (void)out_size; (void)ws_size;
  const float* x2    = (const float*)d_in[0];
  const float* x1    = (const float*)d_in[1];
  const float* g2c   = (const float*)d_in[3];
  const float* b2c   = (const float*)d_in[4];
  const float* g2r   = (const float*)d_in[5];
  const float* b2r   = (const float*)d_in[6];
  const float* W2cur = (const float*)d_in[7];
  const float* W2ref = (const float*)d_in[8];
  const float* bias2 = (const float*)d_in[9];
  const float* convw2= (const float*)d_in[10];
  const float* bns2  = (const float*)d_in[11];
  const float* bnb2  = (const float*)d_in[12];
  const float* g1c   = (const float*)d_in[13];
  const float* b1c   = (const float*)d_in[14];
  const float* g1r   = (const float*)d_in[15];
  const float* b1r   = (const float*)d_in[16];
  const float* W1cur = (const float*)d_in[17];
  const float* W1ref = (const float*)d_in[18];
  const float* bias1 = (const float*)d_in[19];
  const float* convw1= (const float*)d_in[20];
  const float* bns1  = (const float*)d_in[21];
  const float* bnb1  = (const float*)d_in[22];

  const int C2 = 128, C1 = 256;
  const int NP2 = 8*64*64, NP1 = 8*32*32;
  const int HW2 = 4096, HW1 = 1024;

  char* ws = (char*)d_ws;
  size_t off = 0;
  auto alloc = [&](size_t bytes){ size_t o = off; off = (off + bytes + 255) & ~(size_t)255; return o; };
  size_t oWtC2 = alloc((size_t)C2*C2*2), oWtR2 = alloc((size_t)C2*C2*2), oWtV2 = alloc((size_t)C2*C2*2);
  size_t oWtC1 = alloc((size_t)C1*C1*2), oWtR1 = alloc((size_t)C1*C1*2), oWtV1 = alloc((size_t)C1*C1*2);
  size_t oColC2 = alloc(C2*4), oBiasC2 = alloc(C2*4), oColR2 = alloc(C2*4), oBiasR2 = alloc(C2*4);
  size_t oColC1 = alloc(C1*4), oBiasC1 = alloc(C1*4), oColR1 = alloc(C1*4), oBiasR1 = alloc(C1*4);

  unsigned short* WtC2 = (unsigned short*)(ws + oWtC2);
  unsigned short* WtR2 = (unsigned short*)(ws + oWtR2);
  unsigned short* WtV2 = (unsigned short*)(ws + oWtV2);
  unsigned short* WtC1 = (unsigned short*)(ws + oWtC1);
  unsigned short* WtR1 = (unsigned short*)(ws + oWtR1);
  unsigned short* WtV1 = (unsigned short*)(ws + oWtV1);
  float* ColC2 = (float*)(ws + oColC2); float* BiasC2 = (float*)(ws + oBiasC2);
  float* ColR2 = (float*)(ws + oColR2); float* BiasR2 = (float*)(ws + oBiasR2);
  float* ColC1 = (float*)(ws + oColC1); float* BiasC1 = (float*)(ws + oBiasC1);
  float* ColR1 = (float*)(ws + oColR1); float* BiasR1 = (float*)(ws + oBiasR1);

  PrepArgs pa;
  pa.W[0]=W2cur;  pa.g[0]=g2c;     pa.Wt[0]=WtC2; pa.C[0]=C2;
  pa.W[1]=W2ref;  pa.g[1]=g2r;     pa.Wt[1]=WtR2; pa.C[1]=C2;
  pa.W[2]=convw2; pa.g[2]=nullptr; pa.Wt[2]=WtV2; pa.C[2]=C2;
  pa.W[3]=W1cur;  pa.g[3]=g1c;     pa.Wt[3]=WtC1; pa.C[3]=C1;
  pa.W[4]=W1ref;  pa.g[4]=g1r;     pa.Wt[4]=WtR1; pa.C[4]=C1;
  pa.W[5]=convw1; pa.g[5]=nullptr; pa.Wt[5]=WtV1; pa.C[5]=C1;
  prep_transpose<<<dim3(8,8,6), 256, 0, stream>>>(pa);

  ColArgs ca;
  ca.W[0]=W2cur; ca.g[0]=g2c; ca.b[0]=b2c; ca.extra[0]=nullptr; ca.ocs[0]=ColC2; ca.obs[0]=BiasC2; ca.C[0]=C2;
  ca.W[1]=W2ref; ca.g[1]=g2r; ca.b[1]=b2r; ca.extra[1]=bias2;   ca.ocs[1]=ColR2; ca.obs[1]=BiasR2; ca.C[1]=C2;
  ca.W[2]=W1cur; ca.g[2]=g1c; ca.b[2]=b1c; ca.extra[2]=nullptr; ca.ocs[2]=ColC1; ca.obs[2]=BiasC1; ca.C[2]=C1;
  ca.W[3]=W1ref; ca.g[3]=g1r; ca.b[3]=b1r; ca.extra[3]=bias1;   ca.ocs[3]=ColR1; ca.obs[3]=BiasR1; ca.C[3]=C1;
  prep_colsum<<<dim3(4, 4), 256, 0, stream>>>(ca);

  float* out2 = (float*)d_out;
  float* out1 = out2 + (size_t)8*C2*HW2;

  fusedv5<128,32><<<NP2/32, 256, 0, stream>>>(
      x2, WtC2, WtR2, WtV2, ColC2, BiasC2, ColR2, BiasR2, bns2, bnb2, out2, HW2);
  fusedv5<256,16><<<NP1/16, 256, 0, stream>>>(
      x1, WtC1, WtR1, WtV1, ColC1, BiasC1, ColR1, BiasR1, bns1, bnb1, out1, HW1);
}